// Round 4
// baseline (941.908 us; speedup 1.0000x reference)
//
#include <hip/hip_runtime.h>

// Attention_14353780703904: B=8, S=2048, D=1024, fp32 in/out.
//   proj = x @ W^T + b ; scores = x @ proj^T ; weights = softmax(scores) ;
//   ctx = weights @ x.  Outputs: [ctx (B*S*D) | weights (B*S*S)] fp32.
//
// R8: R7 minus the XCD swizzle (measured: swizzle caused 2.5x write
// amplification -- one batch's 16MB write set per 4MB L2 -> thrash; natural
// dispatch order already co-locates same-B-panel blocks per XCD). Keeps:
//  - unroll-by-3 triple-buffer rotation w/ compile-time buffer pointers
//    (ds addresses fold to base + offset immediates -> VALU cut).
//  - single barrier + counted vmcnt per k-iter (never 0 in main loop).
//  - hi-cluster then lo-cluster MFMA; per-acc op order unchanged ->
//    bitwise-identical numerics (absmax 0.0546875 expected).
//  - transpose reads x_hi f16 (33.5 MB) instead of x fp32 (67 MB).

typedef _Float16 f16;
typedef _Float16 f16x8 __attribute__((ext_vector_type(8)));
typedef _Float16 f16x4 __attribute__((ext_vector_type(4)));
typedef float f32x4 __attribute__((ext_vector_type(4)));
typedef unsigned int u32;

#define AS1 __attribute__((address_space(1)))
#define AS3 __attribute__((address_space(3)))

static constexpr int Bb = 8, Ss = 2048, Dd = 1024;

// ---------------- split cast: fp32 -> (hi, lo) fp16 ----------------
__global__ __launch_bounds__(256) void split_cast_k(
    const float* __restrict__ in, f16* __restrict__ hi, f16* __restrict__ lo,
    size_t n4) {
  size_t i = (size_t)blockIdx.x * 256 + threadIdx.x;
  if (i >= n4) return;
  float4 v = ((const float4*)in)[i];
  f16x4 h, l;
  h[0] = (f16)v.x; l[0] = (f16)(v.x - (float)h[0]);
  h[1] = (f16)v.y; l[1] = (f16)(v.y - (float)h[1]);
  h[2] = (f16)v.z; l[2] = (f16)(v.z - (float)h[2]);
  h[3] = (f16)v.w; l[3] = (f16)(v.w - (float)h[3]);
  ((f16x4*)hi)[i] = h;
  ((f16x4*)lo)[i] = l;
}

// ---------------- plain cast: fp32 -> fp16 ----------------
__global__ __launch_bounds__(256) void cast_k(const float* __restrict__ in,
                                              f16* __restrict__ out,
                                              size_t n4) {
  size_t i = (size_t)blockIdx.x * 256 + threadIdx.x;
  if (i >= n4) return;
  float4 v = ((const float4*)in)[i];
  f16x4 h;
  h[0] = (f16)v.x; h[1] = (f16)v.y; h[2] = (f16)v.z; h[3] = (f16)v.w;
  ((f16x4*)out)[i] = h;
}

// ---------------- transpose f16: x_hi[b][s][d] -> xT[b][d][s] --------------
// Values identical to (f16)x — x_hi IS (f16)x. 64x64 tile, 256 threads.
__global__ __launch_bounds__(256) void transpose_f16_k(
    const f16* __restrict__ xh, f16* __restrict__ xT) {
  __shared__ f16 tile[64][72];  // +8 f16 pad
  const int b = blockIdx.z;
  const int s0 = blockIdx.x * 64, d0 = blockIdx.y * 64;
  const int tx = threadIdx.x & 15, ty = threadIdx.x >> 4;  // 16 x 16
  const f16* xb = xh + (size_t)b * Ss * Dd;
#pragma unroll
  for (int r = 0; r < 64; r += 16) {
    f16x4 v = *(const f16x4*)&xb[(size_t)(s0 + ty + r) * Dd + d0 + tx * 4];
    *(f16x4*)&tile[ty + r][tx * 4] = v;
  }
  __syncthreads();
  f16* xTb = xT + (size_t)b * Dd * Ss;
#pragma unroll
  for (int r = 0; r < 64; r += 16) {
    f16x4 o;
#pragma unroll
    for (int i = 0; i < 4; ++i) o[i] = tile[tx * 4 + i][ty + r];
    *(f16x4*)&xTb[(size_t)(d0 + ty + r) * Ss + s0 + tx * 4] = o;
  }
}

// ---------------- stage panels in MFMA-fragment order ----------------------
// Panel p = 16 rows x 32 k = 1024B, stored so lane l holds element
// (row p*16+(l&15), k (l>>4)*8 .. +7) at panel_base + l*16.  Fragment
// reads are then ds_read_b128 at base+lane*16: zero bank conflicts
// (verified R2). Global side: 16 rows x 64B per instruction.
template <int PPW>
__device__ __forceinline__ void stage_tile(const f16* __restrict__ g,
                                           size_t ld, f16* lds, int wave,
                                           int lane) {
#pragma unroll
  for (int c = 0; c < PPW; ++c) {
    int panel = wave * PPW + c;
    const f16* gp =
        g + (size_t)(panel * 16 + (lane & 15)) * ld + (lane >> 4) * 8;
    AS3 u32* lp = (AS3 u32*)(lds + panel * 512);
    __builtin_amdgcn_global_load_lds((const AS1 u32*)gp, lp, 16, 0, 0);
  }
}

// ---------------- K-iteration body (compile-time buffer pointers) ----------
template <bool DUAL_A>
__device__ __forceinline__ void k_body(int it, int nIter,
                                       const f16* __restrict__ Ah,
                                       const f16* __restrict__ Al,
                                       const f16* __restrict__ Bp, int K,
                                       f16* cur, f16* stg, int wave, int lane,
                                       int pA, int pB, f32x4 (&acc)[4][8]) {
  constexpr int BOFF = DUAL_A ? 16384 : 8192;
  // Validate stage `it` (issued 2 iters ago); own stage-it+1 loads stay in
  // flight across the barrier. Only the last iter drains to 0.
  if (it < nIter - 1) {
    if constexpr (DUAL_A)
      asm volatile("s_waitcnt vmcnt(6)" ::: "memory");
    else
      asm volatile("s_waitcnt vmcnt(4)" ::: "memory");
  } else {
    asm volatile("s_waitcnt vmcnt(0)" ::: "memory");
  }
  __builtin_amdgcn_s_barrier();
  asm volatile("" ::: "memory");
  if (it + 2 < nIter) {
    const int k = (it + 2) * 32;
    stage_tile<2>(Ah + k, K, stg, wave, lane);
    if constexpr (DUAL_A) stage_tile<2>(Al + k, K, stg + 8192, wave, lane);
    stage_tile<2>(Bp + k, K, stg + BOFF, wave, lane);
  }
  f16x8 ah[4], al[4], bf[4], bg[4];
#pragma unroll
  for (int i = 0; i < 4; ++i)
    ah[i] = *(const f16x8*)&cur[(pA + i) * 512 + lane * 8];
  if constexpr (DUAL_A) {
#pragma unroll
    for (int i = 0; i < 4; ++i)
      al[i] = *(const f16x8*)&cur[8192 + (pA + i) * 512 + lane * 8];
  }
#pragma unroll
  for (int j = 0; j < 4; ++j)
    bf[j] = *(const f16x8*)&cur[BOFF + (pB + j) * 512 + lane * 8];
#pragma unroll
  for (int j = 0; j < 4; ++j)
    bg[j] = *(const f16x8*)&cur[BOFF + (pB + 4 + j) * 512 + lane * 8];
  __builtin_amdgcn_s_setprio(1);
#pragma unroll
  for (int j = 0; j < 4; ++j)
#pragma unroll
    for (int i = 0; i < 4; ++i)
      acc[i][j] = __builtin_amdgcn_mfma_f32_16x16x32_f16(ah[i], bf[j],
                                                         acc[i][j], 0, 0, 0);
#pragma unroll
  for (int j = 0; j < 4; ++j)
#pragma unroll
    for (int i = 0; i < 4; ++i)
      acc[i][4 + j] = __builtin_amdgcn_mfma_f32_16x16x32_f16(
          ah[i], bg[j], acc[i][4 + j], 0, 0, 0);
  if constexpr (DUAL_A) {
#pragma unroll
    for (int j = 0; j < 4; ++j)
#pragma unroll
      for (int i = 0; i < 4; ++i)
        acc[i][j] = __builtin_amdgcn_mfma_f32_16x16x32_f16(al[i], bf[j],
                                                           acc[i][j], 0, 0, 0);
#pragma unroll
    for (int j = 0; j < 4; ++j)
#pragma unroll
      for (int i = 0; i < 4; ++i)
        acc[i][4 + j] = __builtin_amdgcn_mfma_f32_16x16x32_f16(
            al[i], bg[j], acc[i][4 + j], 0, 0, 0);
  }
  __builtin_amdgcn_s_setprio(0);
}

// ---------------- batched C = A * B^T (+bias) ------------------------------
// DUAL_A: C = (A0 + A1) * B0^T (two A segments share one staged B tile).
// A: [M][K] f16, B: [N][K] f16, C fp32 [M][ldc] or f16 (OUT_F16).
// Block tile 256(M) x 256(N), BK=32; 8 waves 4x2, wave tile 64x128.
// Triple-buffered LDS, counted vmcnt, unroll-by-3; natural block order
// (measured: XCD batch-swizzle caused 2.5x write amplification, R7).
// grid: (N/256, M/256, batch), 512 threads.
template <bool DUAL_A, bool OUT_F16>
__global__ __launch_bounds__(512, 2) void gemm_bt(
    const f16* __restrict__ A0, const f16* __restrict__ A1,
    const f16* __restrict__ B0, float* __restrict__ C, f16* __restrict__ Ch,
    const float* __restrict__ bias, int K, size_t ldc, size_t sA, size_t sB,
    size_t sC) {
  extern __shared__ f16 smem[];
  const int tid = threadIdx.x;
  const int wave = tid >> 6, lane = tid & 63;
  const size_t tn = (size_t)blockIdx.x * 256;
  const size_t tm = (size_t)blockIdx.y * 256;
  const int b = blockIdx.z;

  constexpr int STAGE = (DUAL_A ? 3 : 2) * 8192;  // f16 elems per stage buffer
  constexpr int BOFF = DUAL_A ? 16384 : 8192;

  const f16* Ah = A0 + (size_t)b * sA + tm * (size_t)K;
  const f16* Al = DUAL_A ? (A1 + (size_t)b * sA + tm * (size_t)K) : nullptr;
  const f16* Bp = B0 + (size_t)b * sB + tn * (size_t)K;

  const int wr = wave >> 1, wc = wave & 1;  // 4 x 2 wave grid
  const int pA = wr * 4;  // A panels [pA, pA+4)   (64 rows)
  const int pB = wc * 8;  // B panels [pB, pB+8)   (128 cols)

  f16* const B0_ = smem;
  f16* const B1_ = smem + STAGE;
  f16* const B2_ = smem + 2 * STAGE;

  auto stage_all = [&](int k, f16* buf) {
    stage_tile<2>(Ah + k, K, buf, wave, lane);
    if constexpr (DUAL_A) stage_tile<2>(Al + k, K, buf + 8192, wave, lane);
    stage_tile<2>(Bp + k, K, buf + BOFF, wave, lane);
  };

  f32x4 acc[4][8] = {};

  const int nIter = K / 32;
  stage_all(0, B0_);
  stage_all(32, B1_);
  int it = 0;
  for (; it + 3 <= nIter; it += 3) {
    k_body<DUAL_A>(it, nIter, Ah, Al, Bp, K, B0_, B2_, wave, lane, pA, pB, acc);
    k_body<DUAL_A>(it + 1, nIter, Ah, Al, Bp, K, B1_, B0_, wave, lane, pA, pB,
                   acc);
    k_body<DUAL_A>(it + 2, nIter, Ah, Al, Bp, K, B2_, B1_, wave, lane, pA, pB,
                   acc);
  }
  for (; it < nIter; ++it) {  // <=2 remainder iters, rotation continues
    f16* cur = (it % 3 == 0) ? B0_ : (it % 3 == 1) ? B1_ : B2_;
    f16* stg = (it % 3 == 0) ? B2_ : (it % 3 == 1) ? B0_ : B1_;
    k_body<DUAL_A>(it, nIter, Ah, Al, Bp, K, cur, stg, wave, lane, pA, pB, acc);
  }

  // epilogue: C/D layout col = lane&15, row = (lane>>4)*4 + reg
  const int wm = wr * 64, wn = wc * 128;
#pragma unroll
  for (int i = 0; i < 4; ++i) {
    size_t row0 = tm + wm + i * 16 + ((lane >> 4) << 2);
#pragma unroll
    for (int j = 0; j < 8; ++j) {
      size_t col = tn + wn + j * 16 + (lane & 15);
      float bj = bias ? bias[col] : 0.f;
#pragma unroll
      for (int r = 0; r < 4; ++r) {
        float v = acc[i][j][r] + bj;
        size_t off = (size_t)b * sC + (row0 + r) * ldc + col;
        if constexpr (OUT_F16)
          Ch[off] = (f16)v;
        else
          C[off] = v;
      }
    }
  }
}

// ---------------- row softmax (2048 cols), in-place fp32 + f16 copy --------
__global__ __launch_bounds__(256) void softmax_k(float* __restrict__ sc,
                                                 f16* __restrict__ wh) {
  const size_t row = blockIdx.x;
  float* p = sc + row * 2048;
  f16* w = wh + row * 2048;
  const int t = threadIdx.x;
  float4 v0 = ((const float4*)p)[t];
  float4 v1 = ((const float4*)p)[256 + t];
  float m = fmaxf(fmaxf(fmaxf(v0.x, v0.y), fmaxf(v0.z, v0.w)),
                  fmaxf(fmaxf(v1.x, v1.y), fmaxf(v1.z, v1.w)));
#pragma unroll
  for (int o = 32; o; o >>= 1) m = fmaxf(m, __shfl_xor(m, o, 64));
  __shared__ float red[4];
  if ((t & 63) == 0) red[t >> 6] = m;
  __syncthreads();
  m = fmaxf(fmaxf(red[0], red[1]), fmaxf(red[2], red[3]));
  v0.x = __expf(v0.x - m);
  v0.y = __expf(v0.y - m);
  v0.z = __expf(v0.z - m);
  v0.w = __expf(v0.w - m);
  v1.x = __expf(v1.x - m);
  v1.y = __expf(v1.y - m);
  v1.z = __expf(v1.z - m);
  v1.w = __expf(v1.w - m);
  float s = v0.x + v0.y + v0.z + v0.w + v1.x + v1.y + v1.z + v1.w;
#pragma unroll
  for (int o = 32; o; o >>= 1) s += __shfl_xor(s, o, 64);
  __shared__ float red2[4];
  if ((t & 63) == 0) red2[t >> 6] = s;
  __syncthreads();
  s = red2[0] + red2[1] + red2[2] + red2[3];
  float inv = 1.0f / s;
  v0.x *= inv; v0.y *= inv; v0.z *= inv; v0.w *= inv;
  v1.x *= inv; v1.y *= inv; v1.z *= inv; v1.w *= inv;
  ((float4*)p)[t] = v0;
  ((float4*)p)[256 + t] = v1;
  f16x4 h0, h1;
  h0[0] = (f16)v0.x; h0[1] = (f16)v0.y; h0[2] = (f16)v0.z; h0[3] = (f16)v0.w;
  h1[0] = (f16)v1.x; h1[1] = (f16)v1.y; h1[2] = (f16)v1.z; h1[3] = (f16)v1.w;
  ((f16x4*)w)[t] = h0;
  ((f16x4*)w)[256 + t] = h1;
}

extern "C" void kernel_launch(void* const* d_in, const int* in_sizes, int n_in,
                              void* d_out, int out_size, void* d_ws,
                              size_t ws_size, hipStream_t stream) {
  (void)in_sizes; (void)n_in; (void)out_size; (void)ws_size;
  const float* x = (const float*)d_in[0];     // [B,S,D]
  const float* W = (const float*)d_in[1];     // [D,D]
  const float* bias = (const float*)d_in[2];  // [D]
  float* ctx = (float*)d_out;                            // [B,S,D]
  float* scores = (float*)d_out + (size_t)Bb * Ss * Dd;  // [B,S,S]

  const size_t nBSD = (size_t)Bb * Ss * Dd;  // 16,777,216
  const size_t nDD = (size_t)Dd * Dd;        // 1,048,576

  f16* p = (f16*)d_ws;
  f16* x_hi = p; p += nBSD;
  f16* x_lo = p; p += nBSD;
  f16* xT   = p; p += nBSD;
  f16* W_hi = p; p += nDD;
  f16* p_hi = p; p += nBSD;
  // attnw [B,S,S] f16 aliases x_hi+x_lo (dead after GEMM2; exact size match)
  f16* attnw = x_hi;
  // total ws use: (4*nBSD + nDD)*2 bytes = ~136 MB

  // one-time opt-in for >64KB dynamic LDS (host-side attr, not captured)
  static bool attr_done = false;
  if (!attr_done) {
    hipFuncSetAttribute(reinterpret_cast<const void*>(&gemm_bt<true, true>),
                        hipFuncAttributeMaxDynamicSharedMemorySize, 147456);
    hipFuncSetAttribute(reinterpret_cast<const void*>(&gemm_bt<true, false>),
                        hipFuncAttributeMaxDynamicSharedMemorySize, 147456);
    hipFuncSetAttribute(reinterpret_cast<const void*>(&gemm_bt<false, false>),
                        hipFuncAttributeMaxDynamicSharedMemorySize, 147456);
    attr_done = true;
  }
  constexpr unsigned LDS_DUAL = 3u * 24576u * 2u;    // 147456 B
  constexpr unsigned LDS_SINGLE = 3u * 16384u * 2u;  // 98304 B

  // casts
  split_cast_k<<<(unsigned)(nBSD / 4 / 256), 256, 0, stream>>>(x, x_hi, x_lo,
                                                               nBSD / 4);
  cast_k<<<(unsigned)(nDD / 4 / 256), 256, 0, stream>>>(W, W_hi, nDD / 4);
  // xT from x_hi (identical f16 values, half the read traffic)
  transpose_f16_k<<<dim3(Ss / 64, Dd / 64, Bb), 256, 0, stream>>>(x_hi, xT);

  // GEMM1: proj = (x_hi + x_lo) @ W_hi^T + b -> f16   M=B*S, N=D, K=D
  gemm_bt<true, true>
      <<<dim3(Dd / 256, (Bb * Ss) / 256, 1), 512, LDS_DUAL, stream>>>(
          x_hi, x_lo, W_hi, nullptr, p_hi, bias, Dd, (size_t)Dd, 0, 0, 0);

  // GEMM2: scores[b] = (x_hi + x_lo)[b] @ p_hi[b]^T -> fp32   M=N=S, K=D
  gemm_bt<true, false>
      <<<dim3(Ss / 256, Ss / 256, Bb), 512, LDS_DUAL, stream>>>(
          x_hi, x_lo, p_hi, scores, nullptr, nullptr, Dd, (size_t)Ss,
          (size_t)Ss * Dd, (size_t)Ss * Dd, (size_t)Ss * Ss);

  // softmax rows, in-place fp32 + f16 copy (into attnw, aliasing dead x_hi)
  softmax_k<<<Bb * Ss, 256, 0, stream>>>(scores, attnw);

  // GEMM4: ctx[b] = attnw[b] @ xT[b]  (B = xT [D][S])   M=S, N=D, K=S
  gemm_bt<false, false>
      <<<dim3(Dd / 256, Ss / 256, Bb), 512, LDS_SINGLE, stream>>>(
          attnw, nullptr, xT, ctx, nullptr, nullptr, Ss, (size_t)Dd,
          (size_t)Ss * Ss, (size_t)Dd * Ss, (size_t)Ss * Dd);
}

// Round 5
// 574.791 us; speedup vs baseline: 1.6387x; 1.6387x over previous
//
#include <hip/hip_runtime.h>

// Attention_14353780703904: B=8, S=2048, D=1024, fp32 in/out.
//   proj = x @ W^T + b ; scores = x @ proj^T ; weights = softmax(scores) ;
//   ctx = weights @ x.  Outputs: [ctx (B*S*D) | weights (B*S*S)] fp32.
//
// R9: revert R7/R8's unroll-by-3 (measured: it overflowed the 256-reg/wave
// budget from __launch_bounds__(512,2) -> scratch spills -> +200MB writes,
// +300MB fetches, VALUBusy 16->6%). Back to R6's rotating-pointer triple
// buffer (VGPR 104 + 128 AGPR = 232, no spill), then apply the m201-style
// FINE phase interleave (the proven lever; R6's 32-MFMA clusters were too
// coarse): per K-iter, 4 phases of {4-8 ds_read_b128, 2 gloads, barrier,
// 16-MFMA setprio cluster, barrier}; counted vmcnt(6) once per iter.
// Per-acc MFMA order (hi before lo) unchanged -> bitwise-identical numerics.

typedef _Float16 f16;
typedef _Float16 f16x8 __attribute__((ext_vector_type(8)));
typedef _Float16 f16x4 __attribute__((ext_vector_type(4)));
typedef float f32x4 __attribute__((ext_vector_type(4)));
typedef unsigned int u32;

#define AS1 __attribute__((address_space(1)))
#define AS3 __attribute__((address_space(3)))

#define FENCE() asm volatile("" ::: "memory")
#define BARRIER()                 \
  do {                            \
    FENCE();                      \
    __builtin_amdgcn_s_barrier(); \
    FENCE();                      \
  } while (0)

static constexpr int Bb = 8, Ss = 2048, Dd = 1024;

// ---------------- split cast: fp32 -> (hi, lo) fp16 ----------------
__global__ __launch_bounds__(256) void split_cast_k(
    const float* __restrict__ in, f16* __restrict__ hi, f16* __restrict__ lo,
    size_t n4) {
  size_t i = (size_t)blockIdx.x * 256 + threadIdx.x;
  if (i >= n4) return;
  float4 v = ((const float4*)in)[i];
  f16x4 h, l;
  h[0] = (f16)v.x; l[0] = (f16)(v.x - (float)h[0]);
  h[1] = (f16)v.y; l[1] = (f16)(v.y - (float)h[1]);
  h[2] = (f16)v.z; l[2] = (f16)(v.z - (float)h[2]);
  h[3] = (f16)v.w; l[3] = (f16)(v.w - (float)h[3]);
  ((f16x4*)hi)[i] = h;
  ((f16x4*)lo)[i] = l;
}

// ---------------- plain cast: fp32 -> fp16 ----------------
__global__ __launch_bounds__(256) void cast_k(const float* __restrict__ in,
                                              f16* __restrict__ out,
                                              size_t n4) {
  size_t i = (size_t)blockIdx.x * 256 + threadIdx.x;
  if (i >= n4) return;
  float4 v = ((const float4*)in)[i];
  f16x4 h;
  h[0] = (f16)v.x; h[1] = (f16)v.y; h[2] = (f16)v.z; h[3] = (f16)v.w;
  ((f16x4*)out)[i] = h;
}

// ---------------- transpose f16: x_hi[b][s][d] -> xT[b][d][s] --------------
// Values identical to (f16)x — x_hi IS (f16)x. 64x64 tile, 256 threads.
__global__ __launch_bounds__(256) void transpose_f16_k(
    const f16* __restrict__ xh, f16* __restrict__ xT) {
  __shared__ f16 tile[64][72];  // +8 f16 pad
  const int b = blockIdx.z;
  const int s0 = blockIdx.x * 64, d0 = blockIdx.y * 64;
  const int tx = threadIdx.x & 15, ty = threadIdx.x >> 4;  // 16 x 16
  const f16* xb = xh + (size_t)b * Ss * Dd;
#pragma unroll
  for (int r = 0; r < 64; r += 16) {
    f16x4 v = *(const f16x4*)&xb[(size_t)(s0 + ty + r) * Dd + d0 + tx * 4];
    *(f16x4*)&tile[ty + r][tx * 4] = v;
  }
  __syncthreads();
  f16* xTb = xT + (size_t)b * Dd * Ss;
#pragma unroll
  for (int r = 0; r < 64; r += 16) {
    f16x4 o;
#pragma unroll
    for (int i = 0; i < 4; ++i) o[i] = tile[tx * 4 + i][ty + r];
    *(f16x4*)&xTb[(size_t)(d0 + ty + r) * Ss + s0 + tx * 4] = o;
  }
}

// ---------------- stage panels in MFMA-fragment order ----------------------
// Panel p = 16 rows x 32 k = 1024B, stored so lane l holds element
// (row p*16+(l&15), k (l>>4)*8 .. +7) at panel_base + l*16.  Fragment
// reads are then ds_read_b128 at base+lane*16: zero bank conflicts
// (verified R2). Global side: 16 rows x 64B per instruction.
// 8 waves, PPW panels per wave -> 16 panels per region (256 rows/cols).
template <int PPW>
__device__ __forceinline__ void stage_tile(const f16* __restrict__ g,
                                           size_t ld, f16* lds, int wave,
                                           int lane) {
#pragma unroll
  for (int c = 0; c < PPW; ++c) {
    int panel = wave * PPW + c;
    const f16* gp =
        g + (size_t)(panel * 16 + (lane & 15)) * ld + (lane >> 4) * 8;
    AS3 u32* lp = (AS3 u32*)(lds + panel * 512);
    __builtin_amdgcn_global_load_lds((const AS1 u32*)gp, lp, 16, 0, 0);
  }
}

// ---------------- batched C = A * B^T (+bias) ------------------------------
// DUAL_A: C = (A0 + A1) * B0^T (two A segments share one staged B tile).
// A: [M][K] f16, B: [N][K] f16, C fp32 [M][ldc] or f16 (OUT_F16).
// Block tile 256(M) x 256(N), BK=32; 8 waves 4x2, wave tile 64x128.
// Triple-buffered LDS (rotating pointers), counted vmcnt once per k-iter,
// 4 fine phases per iter: {reads, gloads, bar, 16-MFMA cluster, bar}.
// grid: (N/256, M/256, batch), 512 threads.
template <bool DUAL_A, bool OUT_F16>
__global__ __launch_bounds__(512, 2) void gemm_bt(
    const f16* __restrict__ A0, const f16* __restrict__ A1,
    const f16* __restrict__ B0, float* __restrict__ C, f16* __restrict__ Ch,
    const float* __restrict__ bias, int K, size_t ldc, size_t sA, size_t sB,
    size_t sC) {
  extern __shared__ f16 smem[];
  const int tid = threadIdx.x;
  const int wave = tid >> 6, lane = tid & 63;
  const size_t tn = (size_t)blockIdx.x * 256;
  const size_t tm = (size_t)blockIdx.y * 256;
  const int b = blockIdx.z;

  constexpr int STAGE = (DUAL_A ? 3 : 2) * 8192;  // f16 elems per stage buffer
  constexpr int BOFF = DUAL_A ? 16384 : 8192;     // B region offset in stage

  const f16* Ah = A0 + (size_t)b * sA + tm * (size_t)K;
  const f16* Al = DUAL_A ? (A1 + (size_t)b * sA + tm * (size_t)K) : nullptr;
  const f16* Bp = B0 + (size_t)b * sB + tn * (size_t)K;

  const int wr = wave >> 1, wc = wave & 1;  // 4 x 2 wave grid
  const int pA = wr * 4;  // A panels [pA, pA+4)   (64 rows)
  const int pB = wc * 8;  // B panels [pB, pB+8)   (128 cols)

  f16* b0 = smem;              // compute buffer (stage it)
  f16* b1 = smem + STAGE;      // stage it+1 (in flight across barrier)
  f16* b2 = smem + 2 * STAGE;  // stage it+2 target

  auto stage_all = [&](int k, f16* buf) {
    stage_tile<2>(Ah + k, K, buf, wave, lane);
    if constexpr (DUAL_A) stage_tile<2>(Al + k, K, buf + 8192, wave, lane);
    stage_tile<2>(Bp + k, K, buf + BOFF, wave, lane);
  };

  f32x4 acc[4][8] = {};

  const int nIter = K / 32;
  stage_all(0, b0);
  stage_all(32, b1);
  for (int it = 0; it < nIter; ++it) {
    const bool pf = (it + 2 < nIter);
    const int kpf = (it + 2) * 32;
    // Validate stage `it`; own stage-it+1 loads (6/4) stay in flight across
    // the barrier. Only the last iter drains to 0.
    if (it < nIter - 1) {
      if constexpr (DUAL_A)
        asm volatile("s_waitcnt vmcnt(6)" ::: "memory");
      else
        asm volatile("s_waitcnt vmcnt(4)" ::: "memory");
    } else {
      asm volatile("s_waitcnt vmcnt(0)" ::: "memory");
    }
    BARRIER();  // stage-it published; b2 (read as cur last iter) free to fill

    f16x8 ah[4], al[4], bf[4], bg[4];

    // ---- P1: reads ah+bf, gload A-hi, cluster ah x bf -> acc[i][0..3] ----
#pragma unroll
    for (int i = 0; i < 4; ++i)
      ah[i] = *(const f16x8*)&b0[(pA + i) * 512 + lane * 8];
#pragma unroll
    for (int j = 0; j < 4; ++j)
      bf[j] = *(const f16x8*)&b0[BOFF + (pB + j) * 512 + lane * 8];
    if (pf) stage_tile<2>(Ah + kpf, K, b2, wave, lane);
    BARRIER();
    __builtin_amdgcn_s_setprio(1);
#pragma unroll
    for (int j = 0; j < 4; ++j)
#pragma unroll
      for (int i = 0; i < 4; ++i)
        acc[i][j] = __builtin_amdgcn_mfma_f32_16x16x32_f16(ah[i], bf[j],
                                                           acc[i][j], 0, 0, 0);
    __builtin_amdgcn_s_setprio(0);
    BARRIER();

    // ---- P2: reads bg, gload A-lo, cluster ah x bg -> acc[i][4..7] -------
#pragma unroll
    for (int j = 0; j < 4; ++j)
      bg[j] = *(const f16x8*)&b0[BOFF + (pB + 4 + j) * 512 + lane * 8];
    if constexpr (DUAL_A) {
      if (pf) stage_tile<2>(Al + kpf, K, b2 + 8192, wave, lane);
    }
    BARRIER();
    __builtin_amdgcn_s_setprio(1);
#pragma unroll
    for (int j = 0; j < 4; ++j)
#pragma unroll
      for (int i = 0; i < 4; ++i)
        acc[i][4 + j] = __builtin_amdgcn_mfma_f32_16x16x32_f16(
            ah[i], bg[j], acc[i][4 + j], 0, 0, 0);
    __builtin_amdgcn_s_setprio(0);
    BARRIER();

    // ---- P3: reads al, gload B, cluster al x bf -> acc[i][0..3] ----------
    if constexpr (DUAL_A) {
#pragma unroll
      for (int i = 0; i < 4; ++i)
        al[i] = *(const f16x8*)&b0[8192 + (pA + i) * 512 + lane * 8];
    }
    if (pf) stage_tile<2>(Bp + kpf, K, b2 + BOFF, wave, lane);
    if constexpr (DUAL_A) {
      BARRIER();
      __builtin_amdgcn_s_setprio(1);
#pragma unroll
      for (int j = 0; j < 4; ++j)
#pragma unroll
        for (int i = 0; i < 4; ++i)
          acc[i][j] = __builtin_amdgcn_mfma_f32_16x16x32_f16(
              al[i], bf[j], acc[i][j], 0, 0, 0);
      __builtin_amdgcn_s_setprio(0);
      BARRIER();

      // ---- P4: cluster al x bg -> acc[i][4..7] ---------------------------
      __builtin_amdgcn_s_setprio(1);
#pragma unroll
      for (int j = 0; j < 4; ++j)
#pragma unroll
        for (int i = 0; i < 4; ++i)
          acc[i][4 + j] = __builtin_amdgcn_mfma_f32_16x16x32_f16(
              al[i], bg[j], acc[i][4 + j], 0, 0, 0);
      __builtin_amdgcn_s_setprio(0);
    }

    f16* t = b0; b0 = b1; b1 = b2; b2 = t;
  }

  // epilogue: C/D layout col = lane&15, row = (lane>>4)*4 + reg
  const int wm = pA * 16, wn = pB * 16;
#pragma unroll
  for (int i = 0; i < 4; ++i) {
    size_t row0 = tm + wm + i * 16 + ((lane >> 4) << 2);
#pragma unroll
    for (int j = 0; j < 8; ++j) {
      size_t col = tn + wn + j * 16 + (lane & 15);
      float bj = bias ? bias[col] : 0.f;
#pragma unroll
      for (int r = 0; r < 4; ++r) {
        float v = acc[i][j][r] + bj;
        size_t off = (size_t)b * sC + (row0 + r) * ldc + col;
        if constexpr (OUT_F16)
          Ch[off] = (f16)v;
        else
          C[off] = v;
      }
    }
  }
}

// ---------------- row softmax (2048 cols), in-place fp32 + f16 copy --------
__global__ __launch_bounds__(256) void softmax_k(float* __restrict__ sc,
                                                 f16* __restrict__ wh) {
  const size_t row = blockIdx.x;
  float* p = sc + row * 2048;
  f16* w = wh + row * 2048;
  const int t = threadIdx.x;
  float4 v0 = ((const float4*)p)[t];
  float4 v1 = ((const float4*)p)[256 + t];
  float m = fmaxf(fmaxf(fmaxf(v0.x, v0.y), fmaxf(v0.z, v0.w)),
                  fmaxf(fmaxf(v1.x, v1.y), fmaxf(v1.z, v1.w)));
#pragma unroll
  for (int o = 32; o; o >>= 1) m = fmaxf(m, __shfl_xor(m, o, 64));
  __shared__ float red[4];
  if ((t & 63) == 0) red[t >> 6] = m;
  __syncthreads();
  m = fmaxf(fmaxf(red[0], red[1]), fmaxf(red[2], red[3]));
  v0.x = __expf(v0.x - m);
  v0.y = __expf(v0.y - m);
  v0.z = __expf(v0.z - m);
  v0.w = __expf(v0.w - m);
  v1.x = __expf(v1.x - m);
  v1.y = __expf(v1.y - m);
  v1.z = __expf(v1.z - m);
  v1.w = __expf(v1.w - m);
  float s = v0.x + v0.y + v0.z + v0.w + v1.x + v1.y + v1.z + v1.w;
#pragma unroll
  for (int o = 32; o; o >>= 1) s += __shfl_xor(s, o, 64);
  __shared__ float red2[4];
  if ((t & 63) == 0) red2[t >> 6] = s;
  __syncthreads();
  s = red2[0] + red2[1] + red2[2] + red2[3];
  float inv = 1.0f / s;
  v0.x *= inv; v0.y *= inv; v0.z *= inv; v0.w *= inv;
  v1.x *= inv; v1.y *= inv; v1.z *= inv; v1.w *= inv;
  ((float4*)p)[t] = v0;
  ((float4*)p)[256 + t] = v1;
  f16x4 h0, h1;
  h0[0] = (f16)v0.x; h0[1] = (f16)v0.y; h0[2] = (f16)v0.z; h0[3] = (f16)v0.w;
  h1[0] = (f16)v1.x; h1[1] = (f16)v1.y; h1[2] = (f16)v1.z; h1[3] = (f16)v1.w;
  ((f16x4*)w)[t] = h0;
  ((f16x4*)w)[256 + t] = h1;
}

extern "C" void kernel_launch(void* const* d_in, const int* in_sizes, int n_in,
                              void* d_out, int out_size, void* d_ws,
                              size_t ws_size, hipStream_t stream) {
  (void)in_sizes; (void)n_in; (void)out_size; (void)ws_size;
  const float* x = (const float*)d_in[0];     // [B,S,D]
  const float* W = (const float*)d_in[1];     // [D,D]
  const float* bias = (const float*)d_in[2];  // [D]
  float* ctx = (float*)d_out;                            // [B,S,D]
  float* scores = (float*)d_out + (size_t)Bb * Ss * Dd;  // [B,S,S]

  const size_t nBSD = (size_t)Bb * Ss * Dd;  // 16,777,216
  const size_t nDD = (size_t)Dd * Dd;        // 1,048,576

  f16* p = (f16*)d_ws;
  f16* x_hi = p; p += nBSD;
  f16* x_lo = p; p += nBSD;
  f16* xT   = p; p += nBSD;
  f16* W_hi = p; p += nDD;
  f16* p_hi = p; p += nBSD;
  // attnw [B,S,S] f16 aliases x_hi+x_lo (dead after GEMM2; exact size match)
  f16* attnw = x_hi;
  // total ws use: (4*nBSD + nDD)*2 bytes = ~136 MB

  // one-time opt-in for >64KB dynamic LDS (host-side attr, not captured)
  static bool attr_done = false;
  if (!attr_done) {
    hipFuncSetAttribute(reinterpret_cast<const void*>(&gemm_bt<true, true>),
                        hipFuncAttributeMaxDynamicSharedMemorySize, 147456);
    hipFuncSetAttribute(reinterpret_cast<const void*>(&gemm_bt<true, false>),
                        hipFuncAttributeMaxDynamicSharedMemorySize, 147456);
    hipFuncSetAttribute(reinterpret_cast<const void*>(&gemm_bt<false, false>),
                        hipFuncAttributeMaxDynamicSharedMemorySize, 147456);
    attr_done = true;
  }
  constexpr unsigned LDS_DUAL = 3u * 24576u * 2u;    // 147456 B
  constexpr unsigned LDS_SINGLE = 3u * 16384u * 2u;  // 98304 B

  // casts
  split_cast_k<<<(unsigned)(nBSD / 4 / 256), 256, 0, stream>>>(x, x_hi, x_lo,
                                                               nBSD / 4);
  cast_k<<<(unsigned)(nDD / 4 / 256), 256, 0, stream>>>(W, W_hi, nDD / 4);
  // xT from x_hi (identical f16 values, half the read traffic)
  transpose_f16_k<<<dim3(Ss / 64, Dd / 64, Bb), 256, 0, stream>>>(x_hi, xT);

  // GEMM1: proj = (x_hi + x_lo) @ W_hi^T + b -> f16   M=B*S, N=D, K=D
  gemm_bt<true, true>
      <<<dim3(Dd / 256, (Bb * Ss) / 256, 1), 512, LDS_DUAL, stream>>>(
          x_hi, x_lo, W_hi, nullptr, p_hi, bias, Dd, (size_t)Dd, 0, 0, 0);

  // GEMM2: scores[b] = (x_hi + x_lo)[b] @ p_hi[b]^T -> fp32   M=N=S, K=D
  gemm_bt<true, false>
      <<<dim3(Ss / 256, Ss / 256, Bb), 512, LDS_DUAL, stream>>>(
          x_hi, x_lo, p_hi, scores, nullptr, nullptr, Dd, (size_t)Ss,
          (size_t)Ss * Dd, (size_t)Ss * Dd, (size_t)Ss * Ss);

  // softmax rows, in-place fp32 + f16 copy (into attnw, aliasing dead x_hi)
  softmax_k<<<Bb * Ss, 256, 0, stream>>>(scores, attnw);

  // GEMM4: ctx[b] = attnw[b] @ xT[b]  (B = xT [D][S])   M=S, N=D, K=S
  gemm_bt<false, false>
      <<<dim3(Dd / 256, Ss / 256, Bb), 512, LDS_SINGLE, stream>>>(
          attnw, nullptr, xT, ctx, nullptr, nullptr, Ss, (size_t)Dd,
          (size_t)Ss * Ss, (size_t)Dd * Ss, (size_t)Ss * Dd);
}